// Round 2
// baseline (512.224 us; speedup 1.0000x reference)
//
#include <hip/hip_runtime.h>

// EdgeFeature: out[b,n,k,:] = concat(central(64), neighbor(64), rel(64), ||rel||^2(1))
// B=4 N=8192 C=64 K=20 -> 655360 edges, row = 193 floats (772 B, dword-aligned).
//
// R2: direct register->global stores. gfx950 global_store_dwordx4 only needs
// 4B alignment; the previous LDS-staging + nontemporal path was the 6x penalty.

typedef float f4v  __attribute__((ext_vector_type(4)));
typedef float f4u  __attribute__((ext_vector_type(4), aligned(4)));  // maybe-unaligned store

#define BLOCK 256
#define EPB   16          // edges per block (16 threads/edge, 4 ch/thread)
#define ROW   193

constexpr int Bc = 4, Nc = 8192, Kc = 20;
constexpr int NK = Nc * Kc;                 // 163840
constexpr int TOTAL_EDGES = Bc * NK;        // 655360

__global__ __launch_bounds__(BLOCK)
void edge_feature_kernel(const float* __restrict__ pc,
                         const int* __restrict__ nn_idx,
                         float* __restrict__ out)
{
    const int tid     = threadIdx.x;
    const int e_local = tid >> 4;        // 0..15
    const int lg      = tid & 15;        // 0..15: 4-channel group
    const int e       = blockIdx.x * EPB + e_local;

    const int b   = e / NK;              // const divisors -> magic mul
    const int rem = e - b * NK;
    const int n   = rem / Kc;

    const int idx = nn_idx[e];

    const f4v* pc4 = (const f4v*)pc;     // pc rows: 64 floats, 256B-aligned
    f4v cen = pc4[(b * Nc + n)   * 16 + lg];
    f4v nbr = pc4[(b * Nc + idx) * 16 + lg];
    f4v rel = nbr - cen;

    float part = rel.x * rel.x + rel.y * rel.y + rel.z * rel.z + rel.w * rel.w;
    part += __shfl_xor(part, 1, 16);
    part += __shfl_xor(part, 2, 16);
    part += __shfl_xor(part, 4, 16);
    part += __shfl_xor(part, 8, 16);

    float* row = out + (size_t)e * ROW;
    const int c0 = lg * 4;
    *(f4u*)(row + c0)        = cen;
    *(f4u*)(row + 64 + c0)   = nbr;
    *(f4u*)(row + 128 + c0)  = rel;
    if (lg == 0) row[192] = part;
}

extern "C" void kernel_launch(void* const* d_in, const int* in_sizes, int n_in,
                              void* d_out, int out_size, void* d_ws, size_t ws_size,
                              hipStream_t stream)
{
    const float* pc     = (const float*)d_in[0];
    const int*   nn_idx = (const int*)d_in[1];
    float*       out    = (float*)d_out;

    const int grid = TOTAL_EDGES / EPB;   // 40960 blocks
    edge_feature_kernel<<<grid, BLOCK, 0, stream>>>(pc, nn_idx, out);
}